// Round 13
// baseline (278.880 us; speedup 1.0000x reference)
//
#include <hip/hip_runtime.h>

// Centroids: argmin_c ||latent[r] - coords[c]||^2, 131072 rows x 2048 coords, D=128.
//
// R13: double waves/SIMD via coord-split. R12 counters: VGPR=64 (fits the
//   64-reg slot -> 8 waves/SIMD capable) but grid 1024 = 4 blocks/CU caps
//   occupancy; in-wave ILP levers (R2/R12 prefetch) are proven null.
//   - each block: 128 rows x HALF the coords (1024). grid 2048 = 8 blocks/CU
//     (VGPR-slot 8, LDS 16KB -> 10). 32-row waves kept (LDS traffic is
//     rows/wave-determined, R10 law -> total unchanged).
//   - per-wave qA identical across the two half-blocks (same rows, same
//     deterministic code) -> int scores comparable; halves write partial
//     {b1,b2,bidx,M} int4; merge kernel (512 blocks) does exact union top-2,
//     writes out + margin worklist. union b2 = max(b2a,b2b,min(b1a,b1b)).
//   - R12's ks-prefetch dropped (null, +regs).
// Kept (validated R9-R12): per-WAVE qA (no latent pre-scan), global qB via
//   redundant block scan in prep, int argmax S = 128*I1+I2+v0 with
//   v0 = rint(c2f*invqA) folded into I2 acc-init, i8 hi/lo 3-pass
//   mfma_i32_16x16x64_i8, gl_lds w=16 dbuf + counted vmcnt(2), de-phase sleep,
//   setprio(1) around MFMA, no-tiebreak butterfly, fp64 refine margin net
//   (M = 1.28/(qA*qB) == 0.01 half-scale units, ~7 sigma).
//
// ws layout (bytes): 0 qB (4B) | 16384 counter | 32768 worklist (128KB) |
//   196608 c2f (8KB) | 262144 Bh (256KB) | 524288 Bl (256KB) |
//   786432 P partials (4MB: 131072 rows x 2 halves x int4) | end 4980736

constexpr int D = 128;
constexpr int C = 2048;
constexpr int CHALF = 1024;        // coords per block (half)
constexpr int NCH = 32;            // coords per chunk
constexpr int NCHUNKS = CHALF / NCH;   // 32
constexpr int WL_CAP = 32768;

constexpr size_t WS_CNT = 16384;
constexpr size_t WS_WL  = 32768;
constexpr size_t WS_C2F = 196608;
constexpr size_t WS_BH  = 262144;
constexpr size_t WS_BL  = 524288;
constexpr size_t WS_P   = 786432;

typedef __attribute__((ext_vector_type(4))) int i32x4;
typedef unsigned int u32;

__device__ __forceinline__ int pack4(int a0, int a1, int a2, int a3) {
    return (int)(((u32)a0 & 255u) | (((u32)a1 & 255u) << 8) |
                 (((u32)a2 & 255u) << 16) | (((u32)a3 & 255u) << 24));
}

// quantize v -> hi (|h|<=127), lo (|l|<=64): v = h*qa + l*qa/128 + eps
__device__ __forceinline__ void q2(float v, float qa, float inv, float inv128,
                                   int* h, int* l) {
    float hf = __builtin_rintf(v * inv);
    *h = (int)hf;
    float r = fmaf(-hf, qa, v);
    *l = (int)__builtin_rintf(r * inv128);
}

// async global->LDS, 16B per lane (wave-uniform base + lane*16: contiguous).
__device__ __forceinline__ void gl_lds16(const void* g, void* l) {
    __builtin_amdgcn_global_load_lds(
        (const __attribute__((address_space(1))) u32*)g,
        (__attribute__((address_space(3))) u32*)l, 16, 0, 0);
}

// ---------------- prep: global qB + int8 B images + c2f ----------------
// 8 blocks x 1024 threads. Each block redundantly scans ALL coords (1 MB,
// L2-broadcast) for the global amax -> identical qB everywhere, no atomics.
// Thread t = (c, p=t&3) quantizes elems p*32..p*32+31 (granules g8 = 2p,2p+1)
// at granule pos g8 ^ (c&7); p==0 writes c2f[c] = -64*c2/qB.
__global__ __launch_bounds__(1024) void prep_coords(
        const float* __restrict__ coords,
        signed char* __restrict__ Bh,
        signed char* __restrict__ Bl,
        float* __restrict__ c2f, float* __restrict__ qBout,
        int* __restrict__ counter) {
    __shared__ float sW[16];
    int t = blockIdx.x * blockDim.x + threadIdx.x;
    if (t == 0) *counter = 0;

    // global amax over all coords (65536 float4 / 1024 threads = 64 each)
    float m = 0.f;
    for (int i = threadIdx.x; i < C * D / 4; i += 1024) {
        float4 v = ((const float4*)coords)[i];
        m = fmaxf(m, fmaxf(fmaxf(fabsf(v.x), fabsf(v.y)),
                           fmaxf(fabsf(v.z), fabsf(v.w))));
    }
#pragma unroll
    for (int s = 1; s <= 32; s <<= 1) m = fmaxf(m, __shfl_xor(m, s, 64));
    if ((threadIdx.x & 63) == 0) sW[threadIdx.x >> 6] = m;
    __syncthreads();
    float aB = 1e-30f;
#pragma unroll
    for (int i = 0; i < 16; ++i) aB = fmaxf(aB, sW[i]);

    float qb = aB * (1.f / 127.f);
    float inv = 127.f / aB;
    float inv128 = inv * 128.f;
    if (t == 0) *qBout = qb;

    int c = t >> 2, p = t & 3;
    float v[32];
#pragma unroll
    for (int i = 0; i < 8; ++i)
        *(float4*)(v + i * 4) = *(const float4*)(coords + (size_t)c * D + p * 32 + i * 4);
    float ss = 0.f;
#pragma unroll
    for (int j = 0; j < 32; ++j) ss = fmaf(v[j], v[j], ss);
#pragma unroll
    for (int s = 1; s <= 2; s <<= 1) ss += __shfl_xor(ss, s, 64);

#pragma unroll
    for (int g = 0; g < 2; ++g) {        // two 16-elem granules
        int g8 = p * 2 + g;
        int hw[4], lw[4];
#pragma unroll
        for (int w = 0; w < 4; ++w) {
            int h0, l0, h1, l1, h2, l2, h3, l3;
            q2(v[g * 16 + w * 4 + 0], qb, inv, inv128, &h0, &l0);
            q2(v[g * 16 + w * 4 + 1], qb, inv, inv128, &h1, &l1);
            q2(v[g * 16 + w * 4 + 2], qb, inv, inv128, &h2, &l2);
            q2(v[g * 16 + w * 4 + 3], qb, inv, inv128, &h3, &l3);
            hw[w] = pack4(h0, h1, h2, h3);
            lw[w] = pack4(l0, l1, l2, l3);
        }
        size_t off = (size_t)c * 128 + (size_t)((g8 ^ (c & 7)) * 16);
        *(i32x4*)(Bh + off) = (i32x4){hw[0], hw[1], hw[2], hw[3]};
        *(i32x4*)(Bl + off) = (i32x4){lw[0], lw[1], lw[2], lw[3]};
    }
    if (p == 0) c2f[c] = -64.f * ss / qb;
}

// ---------------- main kernel (one half of the coords per block) ----------------

__global__ __launch_bounds__(256, 2) void centroid_fast(
        const float* __restrict__ latent,
        const signed char* __restrict__ Bh_img,
        const signed char* __restrict__ Bl_img,
        const float* __restrict__ c2f,
        const float* __restrict__ qBp,
        int4* __restrict__ P) {
    // dbuf 2x4KB hi + 2x4KB lo = 16 KB; 8 blocks/CU if VGPR <= 64 (grid 2048)
    __shared__ __align__(16) signed char Bh[2][NCH * 128], Bl[2][NCH * 128];

    const int tid  = threadIdx.x;
    const int wid  = tid >> 6;            // wave 0..3 -> rows wid*32..wid*32+31
    const int lane = tid & 63;
    const int q    = lane >> 4, lr = lane & 15;
    const int bid  = blockIdx.x;
    const int rb   = bid >> 1;            // row-block
    const int half = bid & 1;             // coord half
    const int row_block = rb * 128;
    const int cbase0 = half * CHALF;      // global coord base for this block
    const size_t ibase = (size_t)cbase0 * 128;   // byte base into images

    // de-phase co-resident blocks (validated R3)
    {
        int ph = (bid ^ (bid >> 8)) & 3;
        for (int i = 0; i < ph * 2; ++i) __builtin_amdgcn_s_sleep(8);
    }

    // ---- prologue: stage chunk 0 (2 gl_lds: 4KB/image = 256thr x 16B) ----
    gl_lds16(Bh_img + ibase + tid * 16, &Bh[0][tid * 16]);
    gl_lds16(Bl_img + ibase + tid * 16, &Bl[0][tid * 16]);

    const float qB = *qBp;

    // ---- A fragments: int8 hi/lo with per-WAVE qA (amax over the wave's 32
    // rows; shfl-only). Identical for both halves of a row-block -> scores
    // comparable. Lane holds rows wid*32 + mt*16 + lr, k = ks*64 + q*16 + 0..15.
    i32x4 Ah[2][2], Al[2][2];
    float invqA, qa;
    {
        float v[2][32];
#pragma unroll
        for (int mt = 0; mt < 2; ++mt) {
            const float* rp = latent + (size_t)(row_block + wid * 32 + mt * 16 + lr) * D;
#pragma unroll
            for (int ks = 0; ks < 2; ++ks)
#pragma unroll
                for (int i = 0; i < 4; ++i)
                    *(float4*)(v[mt] + ks * 16 + i * 4) =
                        *(const float4*)(rp + ks * 64 + q * 16 + i * 4);
        }
        float amax = 0.f;
#pragma unroll
        for (int mt = 0; mt < 2; ++mt)
#pragma unroll
            for (int j = 0; j < 32; ++j) amax = fmaxf(amax, fabsf(v[mt][j]));
#pragma unroll
        for (int s = 1; s <= 32; s <<= 1) amax = fmaxf(amax, __shfl_xor(amax, s, 64));
        amax = fmaxf(amax, 1e-30f);
        qa = amax * (1.f / 127.f);
        invqA = 1.f / qa;
        float inv = 127.f / amax;
        float inv128 = inv * 128.f;
#pragma unroll
        for (int mt = 0; mt < 2; ++mt)
#pragma unroll
            for (int ks = 0; ks < 2; ++ks) {
                int hw[4], lw[4];
#pragma unroll
                for (int w = 0; w < 4; ++w) {
                    int h0, l0, h1, l1, h2, l2, h3, l3;
                    q2(v[mt][ks * 16 + w * 4 + 0], qa, inv, inv128, &h0, &l0);
                    q2(v[mt][ks * 16 + w * 4 + 1], qa, inv, inv128, &h1, &l1);
                    q2(v[mt][ks * 16 + w * 4 + 2], qa, inv, inv128, &h2, &l2);
                    q2(v[mt][ks * 16 + w * 4 + 3], qa, inv, inv128, &h3, &l3);
                    hw[w] = pack4(h0, h1, h2, h3);
                    lw[w] = pack4(l0, l1, l2, l3);
                }
                Ah[mt][ks] = (i32x4){hw[0], hw[1], hw[2], hw[3]};
                Al[mt][ks] = (i32x4){lw[0], lw[1], lw[2], lw[3]};
            }
    }
    const int M_int = (int)(1.28f / (qa * qB)) + 1;   // margin 0.01 half-scale

    // int argmax state over S = 128*I1 + I2 + v0 (== argmin distance), 8 slots
    int b1[8], b2[8], bidx[8];
#pragma unroll
    for (int s = 0; s < 8; ++s) {
        b1[s] = -2147483647 - 1; b2[s] = -2147483647 - 1; bidx[s] = 0;
    }

    __syncthreads();   // full drain: chunk-0 stage + A loads visible

    for (int ch = 0; ch < NCHUNKS; ++ch) {
        const int buf = ch & 1;
        const int chbase = cbase0 + ch * NCH;
        // issue next chunk's stage FIRST, then counted wait on current's 2
        if (ch + 1 < NCHUNKS) {
            const size_t off = ibase + (size_t)(ch + 1) * (NCH * 128);
            gl_lds16(Bh_img + off + tid * 16, &Bh[buf ^ 1][tid * 16]);
            gl_lds16(Bl_img + off + tid * 16, &Bl[buf ^ 1][tid * 16]);
            asm volatile("s_waitcnt vmcnt(2)" ::: "memory");
        } else {
            asm volatile("s_waitcnt vmcnt(0)" ::: "memory");
        }
        __builtin_amdgcn_s_barrier();

        // per-chunk c2f (L2-resident 8KB; consumed in the epilogues)
        float cf[2];
        cf[0] = c2f[chbase + lr];
        cf[1] = c2f[chbase + 16 + lr];

#pragma unroll
        for (int nt = 0; nt < 2; ++nt) {
            const int nl = nt * 16 + lr;
            const int v0 = (int)__builtin_rintf(cf[nt] * invqA);
            i32x4 I1[2], I2[2];
#pragma unroll
            for (int mt = 0; mt < 2; ++mt) {
                I1[mt] = (i32x4){0, 0, 0, 0};
                I2[mt] = (i32x4){v0, v0, v0, v0};   // c2 folded into acc init
            }
            __builtin_amdgcn_s_setprio(1);
#pragma unroll
            for (int ks = 0; ks < 2; ++ks) {
                const int e = nl * 128 + (((ks << 2) | q) ^ (lr & 7)) * 16;
                i32x4 bh = *(const i32x4*)(&Bh[buf][e]);
                i32x4 bl = *(const i32x4*)(&Bl[buf][e]);
#pragma unroll
                for (int mt = 0; mt < 2; ++mt)
                    I1[mt] = __builtin_amdgcn_mfma_i32_16x16x64_i8(Ah[mt][ks], bh, I1[mt], 0, 0, 0);
#pragma unroll
                for (int mt = 0; mt < 2; ++mt)
                    I2[mt] = __builtin_amdgcn_mfma_i32_16x16x64_i8(Ah[mt][ks], bl, I2[mt], 0, 0, 0);
#pragma unroll
                for (int mt = 0; mt < 2; ++mt)
                    I2[mt] = __builtin_amdgcn_mfma_i32_16x16x64_i8(Al[mt][ks], bh, I2[mt], 0, 0, 0);
            }
            __builtin_amdgcn_s_setprio(0);
            const int n_global = chbase + nl;
            // pure-int epilogue: 6 VALU/score
#pragma unroll
            for (int mt = 0; mt < 2; ++mt)
#pragma unroll
                for (int r = 0; r < 4; ++r) {
                    int slot = mt * 4 + r;
                    int S = (int)(((u32)I1[mt][r] << 7) + (u32)I2[mt][r]);
                    bool gt  = S > b1[slot];
                    b2[slot]   = max(b2[slot], min(S, b1[slot]));
                    b1[slot]   = max(S, b1[slot]);
                    bidx[slot] = gt ? n_global : bidx[slot];
                }
        }
        __builtin_amdgcn_s_barrier();   // all reads of buf done before restage
    }

    // butterfly over the 16 col-residue lanes (int max semantics)
#pragma unroll
    for (int m = 1; m <= 8; m <<= 1) {
#pragma unroll
        for (int s = 0; s < 8; ++s) {
            int oa = __shfl_xor(b1[s], m, 64);
            int ob = __shfl_xor(b2[s], m, 64);
            int oi = __shfl_xor(bidx[s], m, 64);
            int mn = min(b1[s], oa);
            b2[s] = max(max(b2[s], ob), mn);
            bool take = oa > b1[s];
            b1[s]   = take ? oa : b1[s];
            bidx[s] = take ? oi : bidx[s];
        }
    }
    // slot s canonical in lane lr==s; write partial {b1, b2, bidx, M}
#pragma unroll
    for (int s = 0; s < 8; ++s) {
        if (lr == s) {
            int row = row_block + wid * 32 + (s >> 2) * 16 + q * 4 + (s & 3);
            P[row * 2 + half] = make_int4(b1[s], b2[s], bidx[s], M_int);
        }
    }
}

// ---------------- merge halves: exact union top-2 + margin worklist ----------------

__global__ __launch_bounds__(256) void merge_halves(
        const int4* __restrict__ P, int* __restrict__ out,
        int* __restrict__ counter, int* __restrict__ worklist) {
    int row = blockIdx.x * 256 + threadIdx.x;
    int4 a = P[row * 2 + 0];
    int4 b = P[row * 2 + 1];
    bool takeB = b.x > a.x;                       // tie -> half 0
    int top = takeB ? b.x : a.x;
    int idx = takeB ? b.z : a.z;
    int sec = max(max(a.y, b.y), min(a.x, b.x));  // union second-best
    out[row] = idx;
    if (top - sec < a.w) {                        // M identical in both halves
        int w = atomicAdd(counter, 1);
        if (w < WL_CAP) worklist[w] = row;
    }
}

// ---------------- fp64 refine (1024 threads, 2 coords/thread) ----------------

__global__ __launch_bounds__(1024) void refine_fp64(
        const float* __restrict__ latent, const float* __restrict__ coords,
        const int* __restrict__ worklist, const int* __restrict__ counter,
        int wl_cap, int* __restrict__ out) {
    __shared__ float  xs[D];
    __shared__ double rv[1024];
    __shared__ int    ri[1024];

    int n = *counter;
    if (n > wl_cap) n = wl_cap;

    for (int wi = blockIdx.x; wi < n; wi += gridDim.x) {
        int row = worklist[wi];
        if (threadIdx.x < D)
            xs[threadIdx.x] = latent[(size_t)row * D + threadIdx.x];
        __syncthreads();

        double best = 1.0e300;
        int    bix  = 0;
        for (int c = threadIdx.x; c < C; c += 1024) {
            const float4* cp = (const float4*)(coords + (size_t)c * D);
            double s0 = 0.0, s1 = 0.0, s2 = 0.0, s3 = 0.0;
#pragma unroll 8
            for (int k4 = 0; k4 < 32; ++k4) {
                float4 v = cp[k4];
                double d0 = (double)xs[k4 * 4 + 0] - (double)v.x;
                double d1 = (double)xs[k4 * 4 + 1] - (double)v.y;
                double d2 = (double)xs[k4 * 4 + 2] - (double)v.z;
                double d3 = (double)xs[k4 * 4 + 3] - (double)v.w;
                s0 = fma(d0, d0, s0); s1 = fma(d1, d1, s1);
                s2 = fma(d2, d2, s2); s3 = fma(d3, d3, s3);
            }
            double s = (s0 + s1) + (s2 + s3);
            if (s < best) { best = s; bix = c; }
        }
        rv[threadIdx.x] = best;
        ri[threadIdx.x] = bix;
        __syncthreads();
        for (int off = 512; off > 0; off >>= 1) {
            if (threadIdx.x < off) {
                double ov = rv[threadIdx.x + off];
                int    oi = ri[threadIdx.x + off];
                if (ov < rv[threadIdx.x] ||
                    (ov == rv[threadIdx.x] && oi < ri[threadIdx.x])) {
                    rv[threadIdx.x] = ov;
                    ri[threadIdx.x] = oi;
                }
            }
            __syncthreads();
        }
        if (threadIdx.x == 0) out[row] = ri[0];
        __syncthreads();
    }
}

extern "C" void kernel_launch(void* const* d_in, const int* in_sizes, int n_in,
                              void* d_out, int out_size, void* d_ws, size_t ws_size,
                              hipStream_t stream) {
    const float* latent = (const float*)d_in[0];
    const float* coords = (const float*)d_in[1];
    int*         out    = (int*)d_out;

    char* ws = (char*)d_ws;
    float*  qB      = (float*)ws;
    int*    counter = (int*)(ws + WS_CNT);
    int*    wl      = (int*)(ws + WS_WL);
    float*  c2f     = (float*)(ws + WS_C2F);
    signed char* Bh = (signed char*)(ws + WS_BH);
    signed char* Bl = (signed char*)(ws + WS_BL);
    int4*   P       = (int4*)(ws + WS_P);
    const int n_rows = in_sizes[0] / D;   // 131072

    prep_coords<<<8, 1024, 0, stream>>>(coords, Bh, Bl, c2f, qB, counter);
    centroid_fast<<<(n_rows / 128) * 2, 256, 0, stream>>>(latent, Bh, Bl, c2f,
                                                          qB, P);
    merge_halves<<<n_rows / 256, 256, 0, stream>>>(P, out, counter, wl);
    refine_fp64<<<608, 1024, 0, stream>>>(latent, coords, wl, counter, WL_CAP, out);
}